// Round 20
// baseline (1288.530 us; speedup 1.0000x reference)
//
#include <hip/hip_runtime.h>

#define T 512
#define HDIM 128
#define LOUT 128
#define KEXT 639
#define KPAD 640
#define BM 4

typedef _Float16 half8 __attribute__((ext_vector_type(8)));
typedef _Float16 half4 __attribute__((ext_vector_type(4)));
typedef _Float16 half2t __attribute__((ext_vector_type(2)));
typedef float f32x4 __attribute__((ext_vector_type(4)));
typedef unsigned int u32x4 __attribute__((ext_vector_type(4)));

__device__ __forceinline__ int clampT(int v) { return v < 0 ? 0 : (v > T ? T : v); }

__device__ __forceinline__ half8 load8f(const float* p) {
  float4 q0 = *(const float4*)p;
  float4 q1 = *(const float4*)(p + 4);
  half8 v;
  v[0] = (_Float16)q0.x; v[1] = (_Float16)q0.y; v[2] = (_Float16)q0.z; v[3] = (_Float16)q0.w;
  v[4] = (_Float16)q1.x; v[5] = (_Float16)q1.y; v[6] = (_Float16)q1.z; v[7] = (_Float16)q1.w;
  return v;
}

// volatile 16B load: executed exactly once -> value must stay resident
__device__ __forceinline__ half8 load8h_once(const _Float16* p) {
  u32x4 raw = *(volatile const u32x4*)p;
  return __builtin_bit_cast(half8, raw);
}

// merged-denominator LSTM cell: 5 exp2 + 2 rcp (was 3 rcp; c-path sigmoids
// share one reciprocal via common denominator -- same real arithmetic)
__device__ __forceinline__ void cell_up(float gi, float gf, float gg, float go,
                                        float& cr, _Float16& hh, bool v) {
  const float A = 1.44269504f, B2 = 2.88539008f;
  const float Fi = __builtin_amdgcn_exp2f(-gi * A);
  const float Ff = __builtin_amdgcn_exp2f(-gf * A);
  const float Fo = __builtin_amdgcn_exp2f(-go * A);
  const float Eg = __builtin_amdgcn_exp2f(gg * B2);
  const float pie = (1.f + Fi) * (1.f + Eg);
  const float pf  = 1.f + Ff;
  const float num = cr * pie + (Eg - 1.f) * pf;
  const float cn  = num * __builtin_amdgcn_rcpf(pf * pie);
  const float ec = __builtin_amdgcn_exp2f(-B2 * __builtin_fabsf(cn));
  const float h  = __builtin_copysignf(
      (1.f - ec) * __builtin_amdgcn_rcpf((1.f + Fo) * (1.f + ec)), cn);
  if (v) { cr = cn; hh = (_Float16)h; }
}

__device__ __forceinline__ float fast_tanh(float x) {
  float ax = __builtin_fabsf(x);
  float e = __builtin_amdgcn_exp2f(ax * -2.88539008f);
  float t = (1.f - e) * __builtin_amdgcn_rcpf(1.f + e);
  return __builtin_copysignf(t, x);
}

// tanh-sum identity (a+q)(1-x)(1+x^2)(1+x^4), x=aq, then fdot2 with Va (fp16)
__device__ __forceinline__ float dotf3(half8 a, half8 q, half8 v, float acc) {
  half8 aq = a * q;
  half8 s2 = a + q;
  half8 x2 = aq * aq;
  half8 x4 = x2 * x2;
  half8 f1 = s2 - s2 * aq;
  half8 f2 = f1 * x2 + f1;
  half8 f3 = f2 * x4 + f2;
  const half2t* fp = (const half2t*)&f3;
  const half2t* vp = (const half2t*)&v;
  acc = __builtin_amdgcn_fdot2(fp[0], vp[0], acc, false);
  acc = __builtin_amdgcn_fdot2(fp[1], vp[1], acc, false);
  acc = __builtin_amdgcn_fdot2(fp[2], vp[2], acc, false);
  acc = __builtin_amdgcn_fdot2(fp[3], vp[3], acc, false);
  return acc;
}

// ---------------------------------------------------------------------------
// Kernel P: one-time fp32 -> fp16 conversion of Whh0 / Wih1 / Whh1
// ---------------------------------------------------------------------------
__global__ __launch_bounds__(256)
void prep_kernel(const float* __restrict__ Whh0, const float* __restrict__ Wih1,
                 const float* __restrict__ Whh1,
                 _Float16* __restrict__ A, _Float16* __restrict__ B,
                 _Float16* __restrict__ C)
{
  const int i = (blockIdx.x * 256 + threadIdx.x) * 4;
  float4 a = *(const float4*)(Whh0 + i);
  float4 b = *(const float4*)(Wih1 + i);
  float4 c = *(const float4*)(Whh1 + i);
  half4 ha = {(_Float16)a.x, (_Float16)a.y, (_Float16)a.z, (_Float16)a.w};
  half4 hb = {(_Float16)b.x, (_Float16)b.y, (_Float16)b.z, (_Float16)b.w};
  half4 hc = {(_Float16)c.x, (_Float16)c.y, (_Float16)c.z, (_Float16)c.w};
  *(half4*)(A + i) = ha;
  *(half4*)(B + i) = hb;
  *(half4*)(C + i) = hc;
}

// ---------------------------------------------------------------------------
// Kernel A: persistent 2-layer LSTM. 64 WGs x 512 threads, 4 batch rows/WG.
// Replicated-A-row MFMA (acc[0] = own gate), one barrier/step, deferred
// global stores, cell constants in LDS. Measured-best configuration.
// ---------------------------------------------------------------------------
__global__ __launch_bounds__(512) __attribute__((amdgpu_waves_per_eu(1, 2)))
void lstm_kernel(const float* __restrict__ x, const float* __restrict__ y,
                 const int* __restrict__ lengths,
                 const float* __restrict__ Wih0,
                 const _Float16* __restrict__ Wh0h,
                 const _Float16* __restrict__ Wi1h,
                 const _Float16* __restrict__ Wh1h,
                 const float* __restrict__ bih0, const float* __restrict__ bhh0,
                 const float* __restrict__ bih1, const float* __restrict__ bhh1,
                 _Float16* __restrict__ Vext, _Float16* __restrict__ Hfin)
{
  const int tid  = threadIdx.x;
  const int w    = tid >> 6;
  const int lane = tid & 63;
  const int fr   = lane & 15;
  const int fg   = lane >> 4;                   // = owned batch row
  const int b0   = blockIdx.x * BM;
  const int u    = w * 16 + fr;                 // owned hidden unit
  const int wpos   = (u >> 3) * 144 + fg * 8 + (u & 7);
  const int frbase = (fr >> 2) * 8;

  __shared__ _Float16 h1buf[2][2304];
  __shared__ _Float16 h2buf[2][2304];
  __shared__ float    xlds[T][BM][3];
  __shared__ float    ylds[LOUT][BM][3];
  __shared__ float    w0lds[512][3];
  __shared__ float    b0lds[512], b1lds[512];
  __shared__ int      lens_s[BM];

  // resident weight fragments (volatile: loaded exactly once)
  half8 wh0[4][4], wi1[4][4], wh1[4][4];
#pragma unroll
  for (int g = 0; g < 4; ++g) {
    const int n = g * 128 + u;
#pragma unroll
    for (int kf = 0; kf < 4; ++kf) {
      const int off = n * HDIM + kf * 32 + fg * 8;
      wh0[g][kf] = load8h_once(Wh0h + off);
      wi1[g][kf] = load8h_once(Wi1h + off);
      wh1[g][kf] = load8h_once(Wh1h + off);
    }
  }

  if (tid < BM) lens_s[tid] = clampT(lengths[b0 + tid]);
  {
    const int n = tid;
    b0lds[n] = bih0[n] + bhh0[n];
    b1lds[n] = bih1[n] + bhh1[n];
    w0lds[n][0] = Wih0[n * 3 + 0];
    w0lds[n][1] = Wih0[n * 3 + 1];
    w0lds[n][2] = Wih0[n * 3 + 2];
  }
  for (int it = tid; it < 2304; it += 512) {
    h1buf[0][it] = (_Float16)0.f; h1buf[1][it] = (_Float16)0.f;
    h2buf[0][it] = (_Float16)0.f; h2buf[1][it] = (_Float16)0.f;
  }
  for (int it = tid; it < BM * T * 3; it += 512) {
    const int b = it / (T * 3), r = it - b * (T * 3);
    xlds[r / 3][b][r % 3] = x[(size_t)(b0 + b) * T * 3 + r];
  }
  for (int it = tid; it < BM * LOUT * 3; it += 512) {
    const int b = it / (LOUT * 3), r = it - b * (LOUT * 3);
    ylds[r / 3][b][r % 3] = y[(size_t)(b0 + b) * LOUT * 3 + r];
  }
  __syncthreads();

  const int mylen_l = lens_s[fg];
  int maxlen = 0;
#pragma unroll
  for (int i = 0; i < BM; ++i) maxlen = max(maxlen, lens_s[i]);
  const int S = maxlen + LOUT - 1;

  for (int t = mylen_l; t < T; ++t)
    Vext[((size_t)(b0 + fg) * KEXT + t) * HDIM + u] = (_Float16)0.f;

  float c1r = 0.f, c2r = 0.f;
  _Float16 h1h = (_Float16)0.f, h2h = (_Float16)0.f, h2p = (_Float16)0.f;
  {
    const float x0 = xlds[0][fg][0], x1 = xlds[0][fg][1], x2 = xlds[0][fg][2];
    float gv[4];
#pragma unroll
    for (int g = 0; g < 4; ++g) {
      const int n = g * 128 + u;
      gv[g] = b0lds[n] + x0 * w0lds[n][0] + x1 * w0lds[n][1] + x2 * w0lds[n][2];
    }
    cell_up(gv[0], gv[1], gv[2], gv[3], c1r, h1h, true);
    h1buf[0][wpos] = h1h;
  }
  __syncthreads();

  for (int s = 0; s < S; ++s) {
    const int p = s & 1;
    // deferred Vext/Hfin store for step s-1
    if (s > 0) {
      const int ps = s - 1;
      if ((ps >= maxlen) || (ps < mylen_l)) {
        const int orow = (ps < maxlen) ? ps : (T + ps - maxlen);
        Vext[((size_t)(b0 + fg) * KEXT + orow) * HDIM + u] = h2p;
      }
      if (ps == maxlen - 1)
        Hfin[(size_t)(b0 + fg) * HDIM + u] = h2p;
    }
    // A-fragments
    half8 h1f[4], h2f[4];
#pragma unroll
    for (int kf = 0; kf < 4; ++kf) {
      const int roff = (kf * 4 + fg) * 144 + frbase;
      h1f[kf] = *(const half8*)&h1buf[p][roff];
      h2f[kf] = *(const half8*)&h2buf[p ^ 1][roff];
    }
    // G1(s) = h1(s)@Wih1^T + h2(s-1)@Whh1^T
    float gv[4];
#pragma unroll
    for (int g = 0; g < 4; ++g) {
      f32x4 a = {0.f, 0.f, 0.f, 0.f};
#pragma unroll
      for (int kf = 0; kf < 4; ++kf)
        a = __builtin_amdgcn_mfma_f32_16x16x32_f16(h1f[kf], wi1[g][kf], a, 0, 0, 0);
#pragma unroll
      for (int kf = 0; kf < 4; ++kf)
        a = __builtin_amdgcn_mfma_f32_16x16x32_f16(h2f[kf], wh1[g][kf], a, 0, 0, 0);
      gv[g] = a[0] + b1lds[g * 128 + u];
    }
    // cell1(s) -> h2(s)
    {
      const bool v1 = (s >= maxlen) || (s < mylen_l);
      cell_up(gv[0], gv[1], gv[2], gv[3], c2r, h2h, v1);
      h2buf[p][wpos] = h2h;
      h2p = h2h;
    }
    if (s + 1 < S) {
      // G0(s+1) = h1(s)@Whh0^T
#pragma unroll
      for (int g = 0; g < 4; ++g) {
        f32x4 a = {0.f, 0.f, 0.f, 0.f};
#pragma unroll
        for (int kf = 0; kf < 4; ++kf)
          a = __builtin_amdgcn_mfma_f32_16x16x32_f16(h1f[kf], wh0[g][kf], a, 0, 0, 0);
        gv[g] = a[0];
      }
      const int k = s + 1;
      const float* xp = (k < maxlen) ? &xlds[k][fg][0] : &ylds[k - maxlen][fg][0];
      const float x0 = xp[0], x1 = xp[1], x2 = xp[2];
#pragma unroll
      for (int g = 0; g < 4; ++g) {
        const int n = g * 128 + u;
        gv[g] += b0lds[n] + x0 * w0lds[n][0] + x1 * w0lds[n][1] + x2 * w0lds[n][2];
      }
      const bool v0 = (k >= maxlen) || (k < mylen_l);
      cell_up(gv[0], gv[1], gv[2], gv[3], c1r, h1h, v0);
      h1buf[p ^ 1][wpos] = h1h;
    }
    __syncthreads();
  }
  {
    const int orow = T + (S - 1) - maxlen;
    Vext[((size_t)(b0 + fg) * KEXT + orow) * HDIM + u] = h2p;
  }
}

// ---------------------------------------------------------------------------
// Kernel B (fused): per 64-key tile, stage Vext rows ONCE in LDS; MFMA from
// LDS -> tA[b][k][h]; emit VT[b][h][k] from the same tile; then tq.
// ---------------------------------------------------------------------------
__global__ __launch_bounds__(256, 1)
void proj_kernel(const _Float16* __restrict__ Vext, const _Float16* __restrict__ Hfin,
                 const float* __restrict__ Wa, const float* __restrict__ bWa,
                 const float* __restrict__ Ua, const float* __restrict__ bUa,
                 _Float16* __restrict__ tA, _Float16* __restrict__ tq,
                 _Float16* __restrict__ VT)
{
  const int b = blockIdx.x;
  const int tid = threadIdx.x;
  const int wave = tid >> 6, lane = tid & 63;
  const int fr = lane & 15, fg = lane >> 4;
  __shared__ _Float16 tile[64][144];

  half8 bf[8][4];
  float bias_r[8];
#pragma unroll
  for (int nt = 0; nt < 8; ++nt) {
    const int ho = nt * 16 + fr;
    bias_r[nt] = bWa[ho];
#pragma unroll
    for (int kf = 0; kf < 4; ++kf)
      bf[nt][kf] = load8f(Wa + ho * HDIM + kf * 32 + fg * 8);
  }

  for (int r = 0; r < 10; ++r) {
    for (int it = tid; it < 1024; it += 256) {
      const int kl = it >> 4, hs = it & 15;
      const int krow = min(r * 64 + kl, KEXT - 1);
      *(half8*)&tile[kl][hs * 8] =
          *(const half8*)(Vext + ((size_t)b * KEXT + krow) * HDIM + hs * 8);
    }
    __syncthreads();
    half8 af[4];
#pragma unroll
    for (int kf = 0; kf < 4; ++kf)
      af[kf] = *(const half8*)&tile[wave * 16 + fr][kf * 32 + fg * 8];
#pragma unroll
    for (int nt = 0; nt < 8; ++nt) {
      f32x4 a = {0.f, 0.f, 0.f, 0.f};
#pragma unroll
      for (int kf = 0; kf < 4; ++kf)
        a = __builtin_amdgcn_mfma_f32_16x16x32_f16(af[kf], bf[nt][kf], a, 0, 0, 0);
#pragma unroll
      for (int j = 0; j < 4; ++j) {
        const int ko = r * 64 + wave * 16 + fg * 4 + j;
        tA[((size_t)b * KPAD + ko) * HDIM + nt * 16 + fr] =
            (_Float16)fast_tanh(a[j] + bias_r[nt]);
      }
    }
    for (int it = tid; it < 1024; it += 256) {
      const int h = it & 127, ks = (it >> 7) * 8;
      half8 v;
#pragma unroll
      for (int e = 0; e < 8; ++e) v[e] = tile[ks + e][h];
      *(half8*)(VT + ((size_t)b * HDIM + h) * KPAD + r * 64 + ks) = v;
    }
    __syncthreads();
  }

#pragma unroll
  for (int nt = 0; nt < 8; ++nt) {
    const int ho = nt * 16 + fr;
    bias_r[nt] = bUa[ho];
#pragma unroll
    for (int kf = 0; kf < 4; ++kf)
      bf[nt][kf] = load8f(Ua + ho * HDIM + kf * 32 + fg * 8);
  }
  for (int r = 0; r < 2; ++r) {
    const int mt = r * 4 + wave;
    const int prow = mt * 16 + fr;
    const _Float16* src = (prow == 0)
        ? (Hfin + (size_t)b * HDIM)
        : (Vext + ((size_t)b * KEXT + 511 + prow) * HDIM);
    half8 af[4];
#pragma unroll
    for (int kf = 0; kf < 4; ++kf) af[kf] = *(const half8*)(src + kf * 32 + fg * 8);
#pragma unroll
    for (int nt = 0; nt < 8; ++nt) {
      f32x4 a = {0.f, 0.f, 0.f, 0.f};
#pragma unroll
      for (int kf = 0; kf < 4; ++kf)
        a = __builtin_amdgcn_mfma_f32_16x16x32_f16(af[kf], bf[nt][kf], a, 0, 0, 0);
#pragma unroll
      for (int j = 0; j < 4; ++j) {
        const int pq = mt * 16 + fg * 4 + j;
        tq[((size_t)b * LOUT + pq) * HDIM + nt * 16 + fr] = (_Float16)fast_tanh(a[j] + bias_r[nt]);
      }
    }
  }
}

// ---------------------------------------------------------------------------
// Kernel C: attention (round-17 version).
// ---------------------------------------------------------------------------
__global__ __launch_bounds__(512)
void attn_kernel(const _Float16* __restrict__ VT,
                 const _Float16* __restrict__ tA,
                 const _Float16* __restrict__ tq,
                 const float* __restrict__ Va,
                 const int* __restrict__ lengths,
                 const float* __restrict__ fc1w, const float* __restrict__ fc1b,
                 const float* __restrict__ fc2w, const float* __restrict__ fc2b,
                 float* __restrict__ out)
{
  const int b = blockIdx.x;
  const int p0 = blockIdx.y * 16;
  const int tid = threadIdx.x, wv = tid >> 6, lane = tid & 63;
  const int fr = lane & 15, fg = lane >> 4;

  __shared__ __align__(16) _Float16 stgS[128 * 136];
  __shared__ __align__(16) _Float16 sc[16 * 656];
  __shared__ __align__(16) _Float16 qs16[16][136];
  __shared__ __align__(16) _Float16 vva[128];
  __shared__ float invs[16];

  for (int it = tid; it < 256; it += 512)
    *(half8*)&qs16[it >> 4][(it & 15) * 8] =
        *(const half8*)(tq + ((size_t)b * LOUT + p0 + (it >> 4)) * HDIM + (it & 15) * 8);
  if (tid < 128) vva[tid] = (_Float16)Va[tid];
  const int len = clampT(lengths[b]);
  const float fb   = (lane < 32) ? fc1b[lane] : 0.f;
  const float w2a  = (lane < 32) ? fc2w[lane] : 0.f;
  const float w2b  = (lane < 32) ? fc2w[32 + lane] : 0.f;
  const float f2b0 = fc2b[0], f2b1 = fc2b[1];
  const _Float16 NEGINF = (_Float16)(-__builtin_inff());
  __syncthreads();

  for (int kc = 0; kc < 5; ++kc) {
    const int ck0 = kc * 128;
    const bool alive = (ck0 < T) ? ((ck0 == 0) || (ck0 < len))
                                 : ((ck0 - T) < p0 + 15);
    if (alive) {
      __syncthreads();
      for (int it = tid; it < 2048; it += 512) {
        const int k = it >> 4, hs = it & 15;
        const int off = k * 136 + ((hs * 8) ^ (((k >> 1) & 7) << 3));
        *(half8*)&stgS[off] =
            *(const half8*)(tA + ((size_t)b * KPAD + ck0 + k) * HDIM + hs * 8);
      }
      __syncthreads();
    }
#pragma unroll
    for (int pp = 0; pp < 2; ++pp) {
      const int prow = wv * 2 + pp;
      const int p = p0 + prow;
      const int k0 = ck0 + lane * 2, k1 = k0 + 1;
      bool anyv;
      if (ck0 < T) {
        const int kmax = min(ck0 + 127, len - 1);
        anyv = (ck0 == 0) || ((ck0 < len) && (kmax > p));
      } else {
        anyv = (ck0 - T) < p;
      }
      if (!anyv) {
        half2t z; z[0] = NEGINF; z[1] = NEGINF;
        *(half2t*)&sc[prow * 656 + k0] = z;
        continue;
      }
      float acc0 = 0.f, acc1 = 0.f;
      const int base0 = (lane * 2) * 136;
      const int base1 = base0 + 136;
      const int sw = (lane & 7) << 3;
#pragma unroll 4
      for (int hb = 0; hb < 16; ++hb) {
        const int ho = (hb * 8) ^ sw;
        const half8 a0 = *(const half8*)&stgS[base0 + ho];
        const half8 a1 = *(const half8*)&stgS[base1 + ho];
        const half8 q8 = *(const half8*)&qs16[prow][hb * 8];
        const half8 v8 = *(const half8*)&vva[hb * 8];
        acc0 = dotf3(a0, q8, v8, acc0);
        acc1 = dotf3(a1, q8, v8, acc1);
      }
      const bool v0 = (k0 < T) ? ((k0 < len) && (k0 == 0 || k0 > p)) : ((k0 - T) < p);
      const bool v1 = (k1 < T) ? ((k1 < len) && (k1 > p)) : ((k1 - T) < p);
      half2t sv;
      sv[0] = v0 ? (_Float16)acc0 : NEGINF;
      sv[1] = v1 ? (_Float16)acc1 : NEGINF;
      *(half2t*)&sc[prow * 656 + k0] = sv;
    }
  }

  const int hcol = wv * 16 + fr;
  const _Float16* vtrow = VT + ((size_t)b * HDIM + hcol) * KPAD;
  half8 vpre[8];
#pragma unroll
  for (int kk = 0; kk < 8; ++kk)
    vpre[kk] = *(const half8*)(vtrow + kk * 32 + fg * 8);

#pragma unroll
  for (int pp = 0; pp < 2; ++pp) {
    const int prow = wv * 2 + pp;
    float m = -__builtin_inff();
    for (int k = lane; k < KPAD; k += 64) m = fmaxf(m, (float)sc[prow * 656 + k]);
#pragma unroll
    for (int off = 32; off; off >>= 1) m = fmaxf(m, __shfl_xor(m, off, 64));
    float ssum = 0.f;
    for (int k = lane; k < KPAD; k += 64) {
      const float e = __builtin_amdgcn_exp2f(((float)sc[prow * 656 + k] - m) * 1.44269504f);
      sc[prow * 656 + k] = (_Float16)e;
      ssum += e;
    }
#pragma unroll
    for (int off = 32; off; off >>= 1) ssum += __shfl_xor(ssum, off, 64);
    if (lane == 0) invs[prow] = __builtin_amdgcn_rcpf(ssum);
  }
  __syncthreads();

  f32x4 cac = {0.f, 0.f, 0.f, 0.f};
#pragma unroll
  for (int kk = 0; kk < 8; ++kk) {
    const half8 av = *(const half8*)&sc[fr * 656 + kk * 32 + fg * 8];
    cac = __builtin_amdgcn_mfma_f32_16x16x32_f16(av, vpre[kk], cac, 0, 0, 0);
  }
#pragma unroll 4
  for (int kk = 8; kk < 20; ++kk) {
    const half8 av = *(const half8*)&sc[fr * 656 + kk * 32 + fg * 8];
    const half8 bv = *(const half8*)(vtrow + kk * 32 + fg * 8);
    cac = __builtin_amdgcn_mfma_f32_16x16x32_f16(av, bv, cac, 0, 0, 0);
  }

  auto ctxs = (float(*)[132])stgS;
  auto f1w  = (_Float16(*)[136])(stgS + 4224);
#pragma unroll
  for (int j = 0; j < 4; ++j) {
    const int pr = fg * 4 + j;
    ctxs[pr][hcol] = cac[j] * invs[pr];
  }
  for (int it = tid; it < 4096; it += 512)
    f1w[it >> 7][it & 127] = (_Float16)fc1w[it];
  __syncthreads();

#pragma unroll
  for (int pp = 0; pp < 2; ++pp) {
    const int prow = wv * 2 + pp;
    float r = 0.f;
    if (lane < 32) {
      float a = fb;
      for (int h = 0; h < HDIM; ++h)
        a = fmaf(ctxs[prow][h], (float)f1w[lane][h], a);
      r = fmaxf(a, 0.f);
    }
    float s0 = r * w2a, s1 = r * w2b;
#pragma unroll
    for (int off = 16; off; off >>= 1) {
      s0 += __shfl_xor(s0, off, 64);
      s1 += __shfl_xor(s1, off, 64);
    }
    if (lane == 0) {
      float* o = out + ((size_t)b * LOUT + p0 + prow) * 2;
      o[0] = s0 + f2b0;
      o[1] = s1 + f2b1;
    }
  }
}

// ---------------------------------------------------------------------------
extern "C" void kernel_launch(void* const* d_in, const int* in_sizes, int n_in,
                              void* d_out, int out_size, void* d_ws, size_t ws_size,
                              hipStream_t stream)
{
  const float* x     = (const float*)d_in[0];
  const float* y     = (const float*)d_in[1];
  const int* lengths = (const int*)d_in[3];
  const float* Wih0  = (const float*)d_in[4];
  const float* Whh0  = (const float*)d_in[5];
  const float* bih0  = (const float*)d_in[6];
  const float* bhh0  = (const float*)d_in[7];
  const float* Wih1  = (const float*)d_in[8];
  const float* Whh1  = (const float*)d_in[9];
  const float* bih1  = (const float*)d_in[10];
  const float* bhh1  = (const float*)d_in[11];
  const float* Wa    = (const float*)d_in[12];
  const float* bWa   = (const float*)d_in[13];
  const float* Ua    = (const float*)d_in[14];
  const float* bUa   = (const float*)d_in[15];
  const float* Va    = (const float*)d_in[16];
  const float* fc1w  = (const float*)d_in[18];
  const float* fc1b  = (const float*)d_in[19];
  const float* fc2w  = (const float*)d_in[20];
  const float* fc2b  = (const float*)d_in[21];

  char* wsp = (char*)d_ws;
  _Float16* Vext  = (_Float16*)(wsp);              // 41,877,504
  _Float16* Hfin  = (_Float16*)(wsp + 41877504);   //     65,536
  _Float16* tA    = (_Float16*)(wsp + 41943040);   // 41,943,040  [b][k][h]
  _Float16* tq    = (_Float16*)(wsp + 83886080);   //  8,388,608
  _Float16* W16_0 = (_Float16*)(wsp + 92274688);   //    131,072
  _Float16* W16_i = (_Float16*)(wsp + 92405760);   //    131,072
  _Float16* W16_1 = (_Float16*)(wsp + 92536832);   //    131,072
  _Float16* VT    = (_Float16*)(wsp + 92667904);   // 41,943,040  [b][h][k]
  (void)in_sizes; (void)n_in; (void)out_size; (void)ws_size;

  prep_kernel<<<64, 256, 0, stream>>>(Whh0, Wih1, Whh1, W16_0, W16_i, W16_1);
  lstm_kernel<<<64, 512, 0, stream>>>(x, y, lengths, Wih0, W16_0, W16_i, W16_1,
                                      bih0, bhh0, bih1, bhh1, Vext, Hfin);
  proj_kernel<<<256, 256, 0, stream>>>(Vext, Hfin, Wa, bWa, Ua, bUa, tA, tq, VT);
  attn_kernel<<<dim3(256, 8), 512, 0, stream>>>(VT, tA, tq, Va, lengths,
                                                fc1w, fc1b, fc2w, fc2b,
                                                (float*)d_out);
}

// Round 21
// 1266.585 us; speedup vs baseline: 1.0173x; 1.0173x over previous
//
#include <hip/hip_runtime.h>

#define T 512
#define HDIM 128
#define LOUT 128
#define KEXT 639
#define KPAD 640
#define BM 4

typedef _Float16 half8 __attribute__((ext_vector_type(8)));
typedef _Float16 half4 __attribute__((ext_vector_type(4)));
typedef _Float16 half2t __attribute__((ext_vector_type(2)));
typedef float f32x4 __attribute__((ext_vector_type(4)));
typedef unsigned int u32x4 __attribute__((ext_vector_type(4)));

__device__ __forceinline__ int clampT(int v) { return v < 0 ? 0 : (v > T ? T : v); }

__device__ __forceinline__ half8 load8f(const float* p) {
  float4 q0 = *(const float4*)p;
  float4 q1 = *(const float4*)(p + 4);
  half8 v;
  v[0] = (_Float16)q0.x; v[1] = (_Float16)q0.y; v[2] = (_Float16)q0.z; v[3] = (_Float16)q0.w;
  v[4] = (_Float16)q1.x; v[5] = (_Float16)q1.y; v[6] = (_Float16)q1.z; v[7] = (_Float16)q1.w;
  return v;
}

// volatile 16B load: executed exactly once -> value must stay resident
__device__ __forceinline__ half8 load8h_once(const _Float16* p) {
  u32x4 raw = *(volatile const u32x4*)p;
  return __builtin_bit_cast(half8, raw);
}

// merged-denominator LSTM cell (r19 champion version: 5 exp2 + 3 rcp)
__device__ __forceinline__ void cell_up(float gi, float gf, float gg, float go,
                                        float& cr, _Float16& hh, bool v) {
  const float A = 1.44269504f, B2 = 2.88539008f;
  const float Fi = __builtin_amdgcn_exp2f(-gi * A);
  const float Ff = __builtin_amdgcn_exp2f(-gf * A);
  const float Fo = __builtin_amdgcn_exp2f(-go * A);
  const float Eg = __builtin_amdgcn_exp2f(gg * B2);
  const float it = (Eg - 1.f) * __builtin_amdgcn_rcpf((1.f + Fi) * (1.f + Eg));
  const float cn = cr * __builtin_amdgcn_rcpf(1.f + Ff) + it;
  const float ec = __builtin_amdgcn_exp2f(-B2 * __builtin_fabsf(cn));
  const float h  = __builtin_copysignf(
      (1.f - ec) * __builtin_amdgcn_rcpf((1.f + Fo) * (1.f + ec)), cn);
  if (v) { cr = cn; hh = (_Float16)h; }
}

__device__ __forceinline__ float fast_tanh(float x) {
  float ax = __builtin_fabsf(x);
  float e = __builtin_amdgcn_exp2f(ax * -2.88539008f);
  float t = (1.f - e) * __builtin_amdgcn_rcpf(1.f + e);
  return __builtin_copysignf(t, x);
}

// tanh-sum identity (a+q)(1-x)(1+x^2)(1+x^4), x=aq, then fdot2 with Va (fp16)
__device__ __forceinline__ float dotf3(half8 a, half8 q, half8 v, float acc) {
  half8 aq = a * q;
  half8 s2 = a + q;
  half8 x2 = aq * aq;
  half8 x4 = x2 * x2;
  half8 f1 = s2 - s2 * aq;
  half8 f2 = f1 * x2 + f1;
  half8 f3 = f2 * x4 + f2;
  const half2t* fp = (const half2t*)&f3;
  const half2t* vp = (const half2t*)&v;
  acc = __builtin_amdgcn_fdot2(fp[0], vp[0], acc, false);
  acc = __builtin_amdgcn_fdot2(fp[1], vp[1], acc, false);
  acc = __builtin_amdgcn_fdot2(fp[2], vp[2], acc, false);
  acc = __builtin_amdgcn_fdot2(fp[3], vp[3], acc, false);
  return acc;
}

// ---------------------------------------------------------------------------
// Kernel P: one-time fp32 -> fp16 conversion of Whh0 / Wih1 / Whh1
// ---------------------------------------------------------------------------
__global__ __launch_bounds__(256)
void prep_kernel(const float* __restrict__ Whh0, const float* __restrict__ Wih1,
                 const float* __restrict__ Whh1,
                 _Float16* __restrict__ A, _Float16* __restrict__ B,
                 _Float16* __restrict__ C)
{
  const int i = (blockIdx.x * 256 + threadIdx.x) * 4;
  float4 a = *(const float4*)(Whh0 + i);
  float4 b = *(const float4*)(Wih1 + i);
  float4 c = *(const float4*)(Whh1 + i);
  half4 ha = {(_Float16)a.x, (_Float16)a.y, (_Float16)a.z, (_Float16)a.w};
  half4 hb = {(_Float16)b.x, (_Float16)b.y, (_Float16)b.z, (_Float16)b.w};
  half4 hc = {(_Float16)c.x, (_Float16)c.y, (_Float16)c.z, (_Float16)c.w};
  *(half4*)(A + i) = ha;
  *(half4*)(B + i) = hb;
  *(half4*)(C + i) = hc;
}

// ---------------------------------------------------------------------------
// Kernel A: persistent 2-layer LSTM. 64 WGs x 512 threads, 4 batch rows/WG.
// Replicated-A-row MFMA (acc[0] = own gate), one barrier/step, deferred
// global stores, cell constants in LDS. Measured-best configuration.
// ---------------------------------------------------------------------------
__global__ __launch_bounds__(512) __attribute__((amdgpu_waves_per_eu(1, 2)))
void lstm_kernel(const float* __restrict__ x, const float* __restrict__ y,
                 const int* __restrict__ lengths,
                 const float* __restrict__ Wih0,
                 const _Float16* __restrict__ Wh0h,
                 const _Float16* __restrict__ Wi1h,
                 const _Float16* __restrict__ Wh1h,
                 const float* __restrict__ bih0, const float* __restrict__ bhh0,
                 const float* __restrict__ bih1, const float* __restrict__ bhh1,
                 _Float16* __restrict__ Vext, _Float16* __restrict__ Hfin)
{
  const int tid  = threadIdx.x;
  const int w    = tid >> 6;
  const int lane = tid & 63;
  const int fr   = lane & 15;
  const int fg   = lane >> 4;                   // = owned batch row
  const int b0   = blockIdx.x * BM;
  const int u    = w * 16 + fr;                 // owned hidden unit
  const int wpos   = (u >> 3) * 144 + fg * 8 + (u & 7);
  const int frbase = (fr >> 2) * 8;

  __shared__ _Float16 h1buf[2][2304];
  __shared__ _Float16 h2buf[2][2304];
  __shared__ float    xlds[T][BM][3];
  __shared__ float    ylds[LOUT][BM][3];
  __shared__ float    w0lds[512][3];
  __shared__ float    b0lds[512], b1lds[512];
  __shared__ int      lens_s[BM];

  // resident weight fragments (volatile: loaded exactly once)
  half8 wh0[4][4], wi1[4][4], wh1[4][4];
#pragma unroll
  for (int g = 0; g < 4; ++g) {
    const int n = g * 128 + u;
#pragma unroll
    for (int kf = 0; kf < 4; ++kf) {
      const int off = n * HDIM + kf * 32 + fg * 8;
      wh0[g][kf] = load8h_once(Wh0h + off);
      wi1[g][kf] = load8h_once(Wi1h + off);
      wh1[g][kf] = load8h_once(Wh1h + off);
    }
  }

  if (tid < BM) lens_s[tid] = clampT(lengths[b0 + tid]);
  {
    const int n = tid;
    b0lds[n] = bih0[n] + bhh0[n];
    b1lds[n] = bih1[n] + bhh1[n];
    w0lds[n][0] = Wih0[n * 3 + 0];
    w0lds[n][1] = Wih0[n * 3 + 1];
    w0lds[n][2] = Wih0[n * 3 + 2];
  }
  for (int it = tid; it < 2304; it += 512) {
    h1buf[0][it] = (_Float16)0.f; h1buf[1][it] = (_Float16)0.f;
    h2buf[0][it] = (_Float16)0.f; h2buf[1][it] = (_Float16)0.f;
  }
  for (int it = tid; it < BM * T * 3; it += 512) {
    const int b = it / (T * 3), r = it - b * (T * 3);
    xlds[r / 3][b][r % 3] = x[(size_t)(b0 + b) * T * 3 + r];
  }
  for (int it = tid; it < BM * LOUT * 3; it += 512) {
    const int b = it / (LOUT * 3), r = it - b * (LOUT * 3);
    ylds[r / 3][b][r % 3] = y[(size_t)(b0 + b) * LOUT * 3 + r];
  }
  __syncthreads();

  const int mylen_l = lens_s[fg];
  int maxlen = 0;
#pragma unroll
  for (int i = 0; i < BM; ++i) maxlen = max(maxlen, lens_s[i]);
  const int S = maxlen + LOUT - 1;

  for (int t = mylen_l; t < T; ++t)
    Vext[((size_t)(b0 + fg) * KEXT + t) * HDIM + u] = (_Float16)0.f;

  float c1r = 0.f, c2r = 0.f;
  _Float16 h1h = (_Float16)0.f, h2h = (_Float16)0.f, h2p = (_Float16)0.f;
  {
    const float x0 = xlds[0][fg][0], x1 = xlds[0][fg][1], x2 = xlds[0][fg][2];
    float gv[4];
#pragma unroll
    for (int g = 0; g < 4; ++g) {
      const int n = g * 128 + u;
      gv[g] = b0lds[n] + x0 * w0lds[n][0] + x1 * w0lds[n][1] + x2 * w0lds[n][2];
    }
    cell_up(gv[0], gv[1], gv[2], gv[3], c1r, h1h, true);
    h1buf[0][wpos] = h1h;
  }
  __syncthreads();

  for (int s = 0; s < S; ++s) {
    const int p = s & 1;
    // deferred Vext/Hfin store for step s-1
    if (s > 0) {
      const int ps = s - 1;
      if ((ps >= maxlen) || (ps < mylen_l)) {
        const int orow = (ps < maxlen) ? ps : (T + ps - maxlen);
        Vext[((size_t)(b0 + fg) * KEXT + orow) * HDIM + u] = h2p;
      }
      if (ps == maxlen - 1)
        Hfin[(size_t)(b0 + fg) * HDIM + u] = h2p;
    }
    // A-fragments
    half8 h1f[4], h2f[4];
#pragma unroll
    for (int kf = 0; kf < 4; ++kf) {
      const int roff = (kf * 4 + fg) * 144 + frbase;
      h1f[kf] = *(const half8*)&h1buf[p][roff];
      h2f[kf] = *(const half8*)&h2buf[p ^ 1][roff];
    }
    // G1(s) = h1(s)@Wih1^T + h2(s-1)@Whh1^T
    float gv[4];
#pragma unroll
    for (int g = 0; g < 4; ++g) {
      f32x4 a = {0.f, 0.f, 0.f, 0.f};
#pragma unroll
      for (int kf = 0; kf < 4; ++kf)
        a = __builtin_amdgcn_mfma_f32_16x16x32_f16(h1f[kf], wi1[g][kf], a, 0, 0, 0);
#pragma unroll
      for (int kf = 0; kf < 4; ++kf)
        a = __builtin_amdgcn_mfma_f32_16x16x32_f16(h2f[kf], wh1[g][kf], a, 0, 0, 0);
      gv[g] = a[0] + b1lds[g * 128 + u];
    }
    // cell1(s) -> h2(s)
    {
      const bool v1 = (s >= maxlen) || (s < mylen_l);
      cell_up(gv[0], gv[1], gv[2], gv[3], c2r, h2h, v1);
      h2buf[p][wpos] = h2h;
      h2p = h2h;
    }
    if (s + 1 < S) {
      // G0(s+1) = h1(s)@Whh0^T
#pragma unroll
      for (int g = 0; g < 4; ++g) {
        f32x4 a = {0.f, 0.f, 0.f, 0.f};
#pragma unroll
        for (int kf = 0; kf < 4; ++kf)
          a = __builtin_amdgcn_mfma_f32_16x16x32_f16(h1f[kf], wh0[g][kf], a, 0, 0, 0);
        gv[g] = a[0];
      }
      const int k = s + 1;
      const float* xp = (k < maxlen) ? &xlds[k][fg][0] : &ylds[k - maxlen][fg][0];
      const float x0 = xp[0], x1 = xp[1], x2 = xp[2];
#pragma unroll
      for (int g = 0; g < 4; ++g) {
        const int n = g * 128 + u;
        gv[g] += b0lds[n] + x0 * w0lds[n][0] + x1 * w0lds[n][1] + x2 * w0lds[n][2];
      }
      const bool v0 = (k >= maxlen) || (k < mylen_l);
      cell_up(gv[0], gv[1], gv[2], gv[3], c1r, h1h, v0);
      h1buf[p ^ 1][wpos] = h1h;
    }
    __syncthreads();
  }
  {
    const int orow = T + (S - 1) - maxlen;
    Vext[((size_t)(b0 + fg) * KEXT + orow) * HDIM + u] = h2p;
  }
}

// ---------------------------------------------------------------------------
// Kernel B (fused): per 64-key tile, stage Vext rows ONCE in LDS; MFMA from
// LDS -> tA[b][k][h]; emit VT[b][h][k] from the same tile; then tq.
// ---------------------------------------------------------------------------
__global__ __launch_bounds__(256, 1)
void proj_kernel(const _Float16* __restrict__ Vext, const _Float16* __restrict__ Hfin,
                 const float* __restrict__ Wa, const float* __restrict__ bWa,
                 const float* __restrict__ Ua, const float* __restrict__ bUa,
                 _Float16* __restrict__ tA, _Float16* __restrict__ tq,
                 _Float16* __restrict__ VT)
{
  const int b = blockIdx.x;
  const int tid = threadIdx.x;
  const int wave = tid >> 6, lane = tid & 63;
  const int fr = lane & 15, fg = lane >> 4;
  __shared__ _Float16 tile[64][144];

  half8 bf[8][4];
  float bias_r[8];
#pragma unroll
  for (int nt = 0; nt < 8; ++nt) {
    const int ho = nt * 16 + fr;
    bias_r[nt] = bWa[ho];
#pragma unroll
    for (int kf = 0; kf < 4; ++kf)
      bf[nt][kf] = load8f(Wa + ho * HDIM + kf * 32 + fg * 8);
  }

  for (int r = 0; r < 10; ++r) {
    for (int it = tid; it < 1024; it += 256) {
      const int kl = it >> 4, hs = it & 15;
      const int krow = min(r * 64 + kl, KEXT - 1);
      *(half8*)&tile[kl][hs * 8] =
          *(const half8*)(Vext + ((size_t)b * KEXT + krow) * HDIM + hs * 8);
    }
    __syncthreads();
    half8 af[4];
#pragma unroll
    for (int kf = 0; kf < 4; ++kf)
      af[kf] = *(const half8*)&tile[wave * 16 + fr][kf * 32 + fg * 8];
#pragma unroll
    for (int nt = 0; nt < 8; ++nt) {
      f32x4 a = {0.f, 0.f, 0.f, 0.f};
#pragma unroll
      for (int kf = 0; kf < 4; ++kf)
        a = __builtin_amdgcn_mfma_f32_16x16x32_f16(af[kf], bf[nt][kf], a, 0, 0, 0);
#pragma unroll
      for (int j = 0; j < 4; ++j) {
        const int ko = r * 64 + wave * 16 + fg * 4 + j;
        tA[((size_t)b * KPAD + ko) * HDIM + nt * 16 + fr] =
            (_Float16)fast_tanh(a[j] + bias_r[nt]);
      }
    }
    for (int it = tid; it < 1024; it += 256) {
      const int h = it & 127, ks = (it >> 7) * 8;
      half8 v;
#pragma unroll
      for (int e = 0; e < 8; ++e) v[e] = tile[ks + e][h];
      *(half8*)(VT + ((size_t)b * HDIM + h) * KPAD + r * 64 + ks) = v;
    }
    __syncthreads();
  }

#pragma unroll
  for (int nt = 0; nt < 8; ++nt) {
    const int ho = nt * 16 + fr;
    bias_r[nt] = bUa[ho];
#pragma unroll
    for (int kf = 0; kf < 4; ++kf)
      bf[nt][kf] = load8f(Ua + ho * HDIM + kf * 32 + fg * 8);
  }
  for (int r = 0; r < 2; ++r) {
    const int mt = r * 4 + wave;
    const int prow = mt * 16 + fr;
    const _Float16* src = (prow == 0)
        ? (Hfin + (size_t)b * HDIM)
        : (Vext + ((size_t)b * KEXT + 511 + prow) * HDIM);
    half8 af[4];
#pragma unroll
    for (int kf = 0; kf < 4; ++kf) af[kf] = *(const half8*)(src + kf * 32 + fg * 8);
#pragma unroll
    for (int nt = 0; nt < 8; ++nt) {
      f32x4 a = {0.f, 0.f, 0.f, 0.f};
#pragma unroll
      for (int kf = 0; kf < 4; ++kf)
        a = __builtin_amdgcn_mfma_f32_16x16x32_f16(af[kf], bf[nt][kf], a, 0, 0, 0);
#pragma unroll
      for (int j = 0; j < 4; ++j) {
        const int pq = mt * 16 + fg * 4 + j;
        tq[((size_t)b * LOUT + pq) * HDIM + nt * 16 + fr] = (_Float16)fast_tanh(a[j] + bias_r[nt]);
      }
    }
  }
}

// ---------------------------------------------------------------------------
// Kernel C: attention (round-17 version).
// ---------------------------------------------------------------------------
__global__ __launch_bounds__(512)
void attn_kernel(const _Float16* __restrict__ VT,
                 const _Float16* __restrict__ tA,
                 const _Float16* __restrict__ tq,
                 const float* __restrict__ Va,
                 const int* __restrict__ lengths,
                 const float* __restrict__ fc1w, const float* __restrict__ fc1b,
                 const float* __restrict__ fc2w, const float* __restrict__ fc2b,
                 float* __restrict__ out)
{
  const int b = blockIdx.x;
  const int p0 = blockIdx.y * 16;
  const int tid = threadIdx.x, wv = tid >> 6, lane = tid & 63;
  const int fr = lane & 15, fg = lane >> 4;

  __shared__ __align__(16) _Float16 stgS[128 * 136];
  __shared__ __align__(16) _Float16 sc[16 * 656];
  __shared__ __align__(16) _Float16 qs16[16][136];
  __shared__ __align__(16) _Float16 vva[128];
  __shared__ float invs[16];

  for (int it = tid; it < 256; it += 512)
    *(half8*)&qs16[it >> 4][(it & 15) * 8] =
        *(const half8*)(tq + ((size_t)b * LOUT + p0 + (it >> 4)) * HDIM + (it & 15) * 8);
  if (tid < 128) vva[tid] = (_Float16)Va[tid];
  const int len = clampT(lengths[b]);
  const float fb   = (lane < 32) ? fc1b[lane] : 0.f;
  const float w2a  = (lane < 32) ? fc2w[lane] : 0.f;
  const float w2b  = (lane < 32) ? fc2w[32 + lane] : 0.f;
  const float f2b0 = fc2b[0], f2b1 = fc2b[1];
  const _Float16 NEGINF = (_Float16)(-__builtin_inff());
  __syncthreads();

  for (int kc = 0; kc < 5; ++kc) {
    const int ck0 = kc * 128;
    const bool alive = (ck0 < T) ? ((ck0 == 0) || (ck0 < len))
                                 : ((ck0 - T) < p0 + 15);
    if (alive) {
      __syncthreads();
      for (int it = tid; it < 2048; it += 512) {
        const int k = it >> 4, hs = it & 15;
        const int off = k * 136 + ((hs * 8) ^ (((k >> 1) & 7) << 3));
        *(half8*)&stgS[off] =
            *(const half8*)(tA + ((size_t)b * KPAD + ck0 + k) * HDIM + hs * 8);
      }
      __syncthreads();
    }
#pragma unroll
    for (int pp = 0; pp < 2; ++pp) {
      const int prow = wv * 2 + pp;
      const int p = p0 + prow;
      const int k0 = ck0 + lane * 2, k1 = k0 + 1;
      bool anyv;
      if (ck0 < T) {
        const int kmax = min(ck0 + 127, len - 1);
        anyv = (ck0 == 0) || ((ck0 < len) && (kmax > p));
      } else {
        anyv = (ck0 - T) < p;
      }
      if (!anyv) {
        half2t z; z[0] = NEGINF; z[1] = NEGINF;
        *(half2t*)&sc[prow * 656 + k0] = z;
        continue;
      }
      float acc0 = 0.f, acc1 = 0.f;
      const int base0 = (lane * 2) * 136;
      const int base1 = base0 + 136;
      const int sw = (lane & 7) << 3;
#pragma unroll 4
      for (int hb = 0; hb < 16; ++hb) {
        const int ho = (hb * 8) ^ sw;
        const half8 a0 = *(const half8*)&stgS[base0 + ho];
        const half8 a1 = *(const half8*)&stgS[base1 + ho];
        const half8 q8 = *(const half8*)&qs16[prow][hb * 8];
        const half8 v8 = *(const half8*)&vva[hb * 8];
        acc0 = dotf3(a0, q8, v8, acc0);
        acc1 = dotf3(a1, q8, v8, acc1);
      }
      const bool v0 = (k0 < T) ? ((k0 < len) && (k0 == 0 || k0 > p)) : ((k0 - T) < p);
      const bool v1 = (k1 < T) ? ((k1 < len) && (k1 > p)) : ((k1 - T) < p);
      half2t sv;
      sv[0] = v0 ? (_Float16)acc0 : NEGINF;
      sv[1] = v1 ? (_Float16)acc1 : NEGINF;
      *(half2t*)&sc[prow * 656 + k0] = sv;
    }
  }

  const int hcol = wv * 16 + fr;
  const _Float16* vtrow = VT + ((size_t)b * HDIM + hcol) * KPAD;
  half8 vpre[8];
#pragma unroll
  for (int kk = 0; kk < 8; ++kk)
    vpre[kk] = *(const half8*)(vtrow + kk * 32 + fg * 8);

#pragma unroll
  for (int pp = 0; pp < 2; ++pp) {
    const int prow = wv * 2 + pp;
    float m = -__builtin_inff();
    for (int k = lane; k < KPAD; k += 64) m = fmaxf(m, (float)sc[prow * 656 + k]);
#pragma unroll
    for (int off = 32; off; off >>= 1) m = fmaxf(m, __shfl_xor(m, off, 64));
    float ssum = 0.f;
    for (int k = lane; k < KPAD; k += 64) {
      const float e = __builtin_amdgcn_exp2f(((float)sc[prow * 656 + k] - m) * 1.44269504f);
      sc[prow * 656 + k] = (_Float16)e;
      ssum += e;
    }
#pragma unroll
    for (int off = 32; off; off >>= 1) ssum += __shfl_xor(ssum, off, 64);
    if (lane == 0) invs[prow] = __builtin_amdgcn_rcpf(ssum);
  }
  __syncthreads();

  f32x4 cac = {0.f, 0.f, 0.f, 0.f};
#pragma unroll
  for (int kk = 0; kk < 8; ++kk) {
    const half8 av = *(const half8*)&sc[fr * 656 + kk * 32 + fg * 8];
    cac = __builtin_amdgcn_mfma_f32_16x16x32_f16(av, vpre[kk], cac, 0, 0, 0);
  }
#pragma unroll 4
  for (int kk = 8; kk < 20; ++kk) {
    const half8 av = *(const half8*)&sc[fr * 656 + kk * 32 + fg * 8];
    const half8 bv = *(const half8*)(vtrow + kk * 32 + fg * 8);
    cac = __builtin_amdgcn_mfma_f32_16x16x32_f16(av, bv, cac, 0, 0, 0);
  }

  auto ctxs = (float(*)[132])stgS;
  auto f1w  = (_Float16(*)[136])(stgS + 4224);
#pragma unroll
  for (int j = 0; j < 4; ++j) {
    const int pr = fg * 4 + j;
    ctxs[pr][hcol] = cac[j] * invs[pr];
  }
  for (int it = tid; it < 4096; it += 512)
    f1w[it >> 7][it & 127] = (_Float16)fc1w[it];
  __syncthreads();

#pragma unroll
  for (int pp = 0; pp < 2; ++pp) {
    const int prow = wv * 2 + pp;
    float r = 0.f;
    if (lane < 32) {
      float a = fb;
      for (int h = 0; h < HDIM; ++h)
        a = fmaf(ctxs[prow][h], (float)f1w[lane][h], a);
      r = fmaxf(a, 0.f);
    }
    float s0 = r * w2a, s1 = r * w2b;
#pragma unroll
    for (int off = 16; off; off >>= 1) {
      s0 += __shfl_xor(s0, off, 64);
      s1 += __shfl_xor(s1, off, 64);
    }
    if (lane == 0) {
      float* o = out + ((size_t)b * LOUT + p0 + prow) * 2;
      o[0] = s0 + f2b0;
      o[1] = s1 + f2b1;
    }
  }
}

// ---------------------------------------------------------------------------
extern "C" void kernel_launch(void* const* d_in, const int* in_sizes, int n_in,
                              void* d_out, int out_size, void* d_ws, size_t ws_size,
                              hipStream_t stream)
{
  const float* x     = (const float*)d_in[0];
  const float* y     = (const float*)d_in[1];
  const int* lengths = (const int*)d_in[3];
  const float* Wih0  = (const float*)d_in[4];
  const float* Whh0  = (const float*)d_in[5];
  const float* bih0  = (const float*)d_in[6];
  const float* bhh0  = (const float*)d_in[7];
  const float* Wih1  = (const float*)d_in[8];
  const float* Whh1  = (const float*)d_in[9];
  const float* bih1  = (const float*)d_in[10];
  const float* bhh1  = (const float*)d_in[11];
  const float* Wa    = (const float*)d_in[12];
  const float* bWa   = (const float*)d_in[13];
  const float* Ua    = (const float*)d_in[14];
  const float* bUa   = (const float*)d_in[15];
  const float* Va    = (const float*)d_in[16];
  const float* fc1w  = (const float*)d_in[18];
  const float* fc1b  = (const float*)d_in[19];
  const float* fc2w  = (const float*)d_in[20];
  const float* fc2b  = (const float*)d_in[21];

  char* wsp = (char*)d_ws;
  _Float16* Vext  = (_Float16*)(wsp);              // 41,877,504
  _Float16* Hfin  = (_Float16*)(wsp + 41877504);   //     65,536
  _Float16* tA    = (_Float16*)(wsp + 41943040);   // 41,943,040  [b][k][h]
  _Float16* tq    = (_Float16*)(wsp + 83886080);   //  8,388,608
  _Float16* W16_0 = (_Float16*)(wsp + 92274688);   //    131,072
  _Float16* W16_i = (_Float16*)(wsp + 92405760);   //    131,072
  _Float16* W16_1 = (_Float16*)(wsp + 92536832);   //    131,072
  _Float16* VT    = (_Float16*)(wsp + 92667904);   // 41,943,040  [b][h][k]
  (void)in_sizes; (void)n_in; (void)out_size; (void)ws_size;

  prep_kernel<<<64, 256, 0, stream>>>(Whh0, Wih1, Whh1, W16_0, W16_i, W16_1);
  lstm_kernel<<<64, 512, 0, stream>>>(x, y, lengths, Wih0, W16_0, W16_i, W16_1,
                                      bih0, bhh0, bih1, bhh1, Vext, Hfin);
  proj_kernel<<<256, 256, 0, stream>>>(Vext, Hfin, Wa, bWa, Ua, bUa, tA, tq, VT);
  attn_kernel<<<dim3(256, 8), 512, 0, stream>>>(VT, tA, tq, Va, lengths,
                                                fc1w, fc1b, fc2w, fc2b,
                                                (float*)d_out);
}